// Round 1
// baseline (94.186 us; speedup 1.0000x reference)
//
#include <hip/hip_runtime.h>

// IoULoss: B=128, N=256, H=W=256.
// inputs: d_in[0]=out f32 [B,2,H,W], d_in[1]=target f32 [B,N,2],
//         d_in[2]=ind i32 [B,N], d_in[3]=mask bool [B,N]
// output: single f32 scalar.

#define BB 128
#define NN 256
#define HWSZ 65536   // H*W = 256*256

// Kernel A: one block per batch (256 threads = 256 n's), partials to ws.
__global__ __launch_bounds__(256) void iou_partial_kernel(
    const float* __restrict__ outp,
    const float* __restrict__ target,
    const int* __restrict__ ind,
    const void* __restrict__ mask,
    float* __restrict__ ws)
{
    const int blk = blockIdx.x;
    const int tid = threadIdx.x;
    const int gid = blk * 256 + tid;          // element index in [0, B*N)
    const int b   = gid >> 8;                 // N == 256

    // ---- mask layout detection (bool-bytes vs int32-staged) ----
    const unsigned char* mb = (const unsigned char*)mask;
    const unsigned char mv8 = mb[gid];        // in-bounds under both layouts
    const int is_bytes = __syncthreads_or(((tid & 3) != 0) && (mv8 != 0));
    bool m;
    if (is_bytes) {
        m = (mv8 != 0);
    } else {
        m = (((const int*)mask)[gid] != 0);
    }

    // ---- gather + compute ----
    const int p = ind[gid];                   // flat index into H*W
    const float dx = outp[(b * 2 + 0) * HWSZ + p];
    const float dy = outp[(b * 2 + 1) * HWSZ + p];
    const float2 t = ((const float2*)target)[gid];
    const float tx = t.x, ty = t.y;

    const float xm = (float)(p & 255);        // p % W
    const float ym = (float)(p >> 8);         // p / W

    const float gx = truncf(xm - tx * 0.5f);
    const float gy = truncf(ym - ty * 0.5f);
    const float px = truncf(xm - dx * 0.5f);
    const float py = truncf(ym - dy * 0.5f);

    // box1 = (gx,gy,tx,ty)  box2 = (px,py,dx,dy), center-offset xywh
    const float b1x1 = gx - tx * 0.5f, b1x2 = gx + tx * 0.5f;
    const float b1y1 = gy - ty * 0.5f, b1y2 = gy + ty * 0.5f;
    const float b2x1 = px - dx * 0.5f, b2x2 = px + dx * 0.5f;
    const float b2y1 = py - dy * 0.5f, b2y2 = py + dy * 0.5f;

    const float iw = fmaxf(fminf(b1x2, b2x2) - fmaxf(b1x1, b2x1), 0.0f);
    const float ih = fmaxf(fminf(b1y2, b2y2) - fmaxf(b1y1, b2y1), 0.0f);
    const float inter = iw * ih;

    const float w1 = b1x2 - b1x1, h1 = b1y2 - b1y1;
    const float w2 = b2x2 - b2x1, h2 = b2y2 - b2y1;
    const float uni = w1 * h1 + 1e-16f + w2 * h2 - inter;
    const float iou = inter / uni;

    float loss = m ? (1.0f - iou) : 0.0f;
    float cnt  = m ? 1.0f : 0.0f;

    // ---- wave (64-lane) shuffle reduce ----
    #pragma unroll
    for (int off = 32; off > 0; off >>= 1) {
        loss += __shfl_down(loss, off);
        cnt  += __shfl_down(cnt,  off);
    }

    // ---- cross-wave via LDS ----
    __shared__ float sl[4];
    __shared__ float sc[4];
    const int wave = tid >> 6;
    if ((tid & 63) == 0) { sl[wave] = loss; sc[wave] = cnt; }
    __syncthreads();
    if (tid == 0) {
        ws[blk]       = sl[0] + sl[1] + sl[2] + sl[3];
        ws[BB + blk]  = sc[0] + sc[1] + sc[2] + sc[3];
    }
}

// Kernel B: reduce 128 partials, write final scalar.
__global__ __launch_bounds__(128) void iou_final_kernel(
    const float* __restrict__ ws, float* __restrict__ out)
{
    const int tid = threadIdx.x;
    float L = ws[tid];
    float C = ws[BB + tid];
    #pragma unroll
    for (int off = 32; off > 0; off >>= 1) {
        L += __shfl_down(L, off);
        C += __shfl_down(C, off);
    }
    __shared__ float sl[2];
    __shared__ float sc[2];
    if ((tid & 63) == 0) { sl[tid >> 6] = L; sc[tid >> 6] = C; }
    __syncthreads();
    if (tid == 0) {
        const float loss = sl[0] + sl[1];
        const float cnt  = sc[0] + sc[1];
        out[0] = loss / (4.0f * cnt + 1e-4f);
    }
}

extern "C" void kernel_launch(void* const* d_in, const int* in_sizes, int n_in,
                              void* d_out, int out_size, void* d_ws, size_t ws_size,
                              hipStream_t stream) {
    const float* outp   = (const float*)d_in[0];
    const float* target = (const float*)d_in[1];
    const int*   ind    = (const int*)d_in[2];
    const void*  mask   = d_in[3];
    float* ws  = (float*)d_ws;
    float* out = (float*)d_out;

    iou_partial_kernel<<<BB, 256, 0, stream>>>(outp, target, ind, mask, ws);
    iou_final_kernel<<<1, 128, 0, stream>>>(ws, out);
}